// Round 1
// 250.517 us; speedup vs baseline: 1.1205x; 1.1205x over previous
//
#include <hip/hip_runtime.h>

constexpr int CIN = 768;
constexpr int CD  = 32;
constexpr int NE  = 8192;
constexpr int M   = 16384;      // B*N = 64*256
constexpr int SCH = 64;         // code chunks for argmin
constexpr int CPC = NE / SCH;   // 128 codes per chunk
constexpr int PTB = 128;        // points per argmin block (4 waves x 32)
#define MARGIN 0.05f

typedef short short8 __attribute__((ext_vector_type(8)));
typedef float f32x4  __attribute__((ext_vector_type(4)));

// RNE split of fp32 into bf16 hi + bf16 lo-residual
__device__ inline void split_bf16(float x, unsigned short& h, unsigned short& l) {
  unsigned u = __float_as_uint(x);
  unsigned hb = (u + 0x7FFFu + ((u >> 16) & 1u)) >> 16;
  float hf = __uint_as_float(hb << 16);
  float r = x - hf;
  unsigned u2 = __float_as_uint(r);
  unsigned lb = (u2 + 0x7FFFu + ((u2 >> 16) & 1u)) >> 16;
  h = (unsigned short)hb;
  l = (unsigned short)lb;
}

// ---------------- fused: compress (blocks 0..511) + codebook (512..1535) ----
// compress: block = 32 rows, 256 threads = 16 row-pairs x 16 K-splits of 48.
//   W_compress staged per 12-K chunk into LDS (wave-uniform reads, broadcast).
//   z loads: 1 float4 per lane, 64 distinct rows/instr -> no broadcast waste.
//   K-split partials reduced via shfl_xor (4 splits/wave) + LDS (4 waves).
__global__ __launch_bounds__(256, 2) void k_pre(
    const float* __restrict__ emb, const float* __restrict__ Wct,
    const float* __restrict__ bct,
    const float* __restrict__ z, const float* __restrict__ Wc,
    const float* __restrict__ bc,
    float* __restrict__ cb, float* __restrict__ cnorm,
    unsigned short* __restrict__ ch, unsigned short* __restrict__ cl,
    float* __restrict__ zc, unsigned short* __restrict__ zh,
    unsigned short* __restrict__ zl) {
  // ws: [16 splits][12 k][36 pad] = 6912 f (27.6 KB); red reuse: [4][32][36] = 4608 f
  __shared__ float smem[6912];
  const int t = threadIdx.x;
  if (blockIdx.x >= 512) {
    // ---- codebook = emb @ W_ct + b_ct ----
    for (int i = t; i < CD * CD; i += 256) smem[i] = Wct[i];
    __syncthreads();
    const int g   = (blockIdx.x - 512) * 256 + t;
    const int row = g >> 5;
    const int col = g & 31;
    float acc = bct[col];
    const float* er = emb + row * CD;
    #pragma unroll
    for (int k = 0; k < CD; ++k) acc = fmaf(er[k], smem[k * CD + col], acc);
    cb[g] = acc;
    unsigned short h, l;
    split_bf16(acc, h, l);
    ch[g] = h; cl[g] = l;
    float v = acc * acc;
    #pragma unroll
    for (int m = 16; m >= 1; m >>= 1) v += __shfl_xor(v, m, 64);
    if (col == 0) cnorm[row] = v;
    return;
  }
  // ---- zc = z @ W_compress + b ----
  const int p   = t & 15;                  // row-pair 0..15
  const int spl = t >> 4;                  // K-split 0..15
  const int wid = t >> 6;                  // wave 0..3
  const int r0  = blockIdx.x * 32;
  const int row = r0 + 2 * p;
  const float* z0 = z + (long)row * CIN + spl * 48;
  const float* z1 = z0 + CIN;
  float acc0[32], acc1[32];
  if (spl == 0) {
    #pragma unroll
    for (int c = 0; c < 32; ++c) { acc0[c] = bc[c]; acc1[c] = bc[c]; }
  } else {
    #pragma unroll
    for (int c = 0; c < 32; ++c) { acc0[c] = 0.f; acc1[c] = 0.f; }
  }
  for (int cch = 0; cch < 4; ++cch) {      // 4 chunks of 12 k per split
    // z prefetch for this chunk (independent of LDS staging)
    float4 a0[3], a1[3];
    #pragma unroll
    for (int q = 0; q < 3; ++q) {
      a0[q] = *(const float4*)(z0 + cch * 12 + q * 4);
      a1[q] = *(const float4*)(z1 + cch * 12 + q * 4);
    }
    // stage W chunk: 16 splits x 12 k x 32 c = 1536 float4
    #pragma unroll
    for (int i = 0; i < 6; ++i) {
      const int f   = t + i * 256;
      const int sp2 = f / 96;
      const int rem = f - sp2 * 96;
      const int kk  = rem >> 3;
      const int c4  = rem & 7;
      const float4 wvv = *(const float4*)(Wc + ((sp2 * 48 + cch * 12 + kk) << 5) + (c4 << 2));
      *(float4*)(smem + sp2 * 432 + kk * 36 + (c4 << 2)) = wvv;
    }
    __syncthreads();
    const float* wsb = smem + spl * 432;
    #pragma unroll
    for (int q = 0; q < 3; ++q) {
      #pragma unroll
      for (int j = 0; j < 4; ++j) {
        const float zk0 = (j == 0) ? a0[q].x : (j == 1) ? a0[q].y : (j == 2) ? a0[q].z : a0[q].w;
        const float zk1 = (j == 0) ? a1[q].x : (j == 1) ? a1[q].y : (j == 2) ? a1[q].z : a1[q].w;
        const float* wr = wsb + (q * 4 + j) * 36;
        #pragma unroll
        for (int c4i = 0; c4i < 8; ++c4i) {
          const float4 wvv = *(const float4*)(wr + (c4i << 2));
          acc0[c4i * 4 + 0] = fmaf(zk0, wvv.x, acc0[c4i * 4 + 0]);
          acc0[c4i * 4 + 1] = fmaf(zk0, wvv.y, acc0[c4i * 4 + 1]);
          acc0[c4i * 4 + 2] = fmaf(zk0, wvv.z, acc0[c4i * 4 + 2]);
          acc0[c4i * 4 + 3] = fmaf(zk0, wvv.w, acc0[c4i * 4 + 3]);
          acc1[c4i * 4 + 0] = fmaf(zk1, wvv.x, acc1[c4i * 4 + 0]);
          acc1[c4i * 4 + 1] = fmaf(zk1, wvv.y, acc1[c4i * 4 + 1]);
          acc1[c4i * 4 + 2] = fmaf(zk1, wvv.z, acc1[c4i * 4 + 2]);
          acc1[c4i * 4 + 3] = fmaf(zk1, wvv.w, acc1[c4i * 4 + 3]);
        }
      }
    }
    __syncthreads();
  }
  // reduce 4 splits within each wave (lanes differ in bits 4,5 of t)
  #pragma unroll
  for (int mk = 16; mk <= 32; mk <<= 1) {
    #pragma unroll
    for (int c = 0; c < 32; ++c) {
      acc0[c] += __shfl_xor(acc0[c], mk, 64);
      acc1[c] += __shfl_xor(acc1[c], mk, 64);
    }
  }
  // wave partials -> LDS (sub-split 0 lanes hold the per-wave sums)
  if (((t >> 4) & 3) == 0) {
    float* rr0 = smem + wid * 1152 + (2 * p) * 36;
    float* rr1 = rr0 + 36;
    #pragma unroll
    for (int c4i = 0; c4i < 8; ++c4i) {
      float4 v0, v1;
      v0.x = acc0[c4i * 4 + 0]; v0.y = acc0[c4i * 4 + 1];
      v0.z = acc0[c4i * 4 + 2]; v0.w = acc0[c4i * 4 + 3];
      v1.x = acc1[c4i * 4 + 0]; v1.y = acc1[c4i * 4 + 1];
      v1.z = acc1[c4i * 4 + 2]; v1.w = acc1[c4i * 4 + 3];
      *(float4*)(rr0 + (c4i << 2)) = v0;
      *(float4*)(rr1 + (c4i << 2)) = v1;
    }
  }
  __syncthreads();
  // gather: 256 threads = 32 rows x 8 col-quads, sum 4 wave-partials, store
  const int grow = t >> 3;
  const int gc4  = t & 7;
  const float* rb = smem + grow * 36 + (gc4 << 2);
  const float4 s0 = *(const float4*)(rb);
  const float4 s1 = *(const float4*)(rb + 1152);
  const float4 s2 = *(const float4*)(rb + 2304);
  const float4 s3 = *(const float4*)(rb + 3456);
  float4 sv;
  sv.x = ((s0.x + s1.x) + s2.x) + s3.x;
  sv.y = ((s0.y + s1.y) + s2.y) + s3.y;
  sv.z = ((s0.z + s1.z) + s2.z) + s3.z;
  sv.w = ((s0.w + s1.w) + s2.w) + s3.w;
  const long idx = (long)(r0 + grow) * CD + (gc4 << 2);
  *(float4*)(zc + idx) = sv;
  ushort4 h4, l4;
  split_bf16(sv.x, h4.x, l4.x);
  split_bf16(sv.y, h4.y, l4.y);
  split_bf16(sv.z, h4.z, l4.z);
  split_bf16(sv.w, h4.w, l4.w);
  *(ushort4*)(zh + idx) = h4;
  *(ushort4*)(zl + idx) = l4;
}

// ---------------- MFMA approx distances + per-chunk argmin ----------------
// grid = (M/PTB=128) x SCH=64 -> 8192 blocks; wave handles 32 points x 128 codes
__global__ __launch_bounds__(256) void k_argmin(
    const unsigned short* __restrict__ zh, const unsigned short* __restrict__ zl,
    const unsigned short* __restrict__ ch, const unsigned short* __restrict__ cl,
    const float* __restrict__ cnorm,
    float* __restrict__ pd, int* __restrict__ pi) {
  const int pb   = blockIdx.x & (M / PTB - 1);   // 0..127
  const int cid  = blockIdx.x >> 7;              // 0..63
  const int lane = threadIdx.x & 63;
  const int wv   = threadIdx.x >> 6;
  const int col  = lane & 15;
  const int quad = lane >> 4;
  const int p0   = pb * PTB + wv * 32;

  const short8 Ah0 = *(const short8*)(zh + (long)(p0 + col) * CD + quad * 8);
  const short8 Al0 = *(const short8*)(zl + (long)(p0 + col) * CD + quad * 8);
  const short8 Ah1 = *(const short8*)(zh + (long)(p0 + 16 + col) * CD + quad * 8);
  const short8 Al1 = *(const short8*)(zl + (long)(p0 + 16 + col) * CD + quad * 8);

  const int jb = cid * CPC;
  float bd0[4], bd1[4];
  int   bj0[4], bj1[4];
  #pragma unroll
  for (int r = 0; r < 4; ++r) { bd0[r] = 1e30f; bd1[r] = 1e30f; bj0[r] = 0; bj1[r] = 0; }

  for (int t = 0; t < CPC / 16; ++t) {           // 8 tiles of 16 codes
    const int cb0 = jb + t * 16;
    const short8 Bh = *(const short8*)(ch + (long)(cb0 + col) * CD + quad * 8);
    const short8 Bl = *(const short8*)(cl + (long)(cb0 + col) * CD + quad * 8);
    f32x4 g0 = {0.f, 0.f, 0.f, 0.f};
    f32x4 g1 = {0.f, 0.f, 0.f, 0.f};
    g0 = __builtin_amdgcn_mfma_f32_16x16x32_bf16(Ah0, Bh, g0, 0, 0, 0);
    g0 = __builtin_amdgcn_mfma_f32_16x16x32_bf16(Ah0, Bl, g0, 0, 0, 0);
    g0 = __builtin_amdgcn_mfma_f32_16x16x32_bf16(Al0, Bh, g0, 0, 0, 0);
    g1 = __builtin_amdgcn_mfma_f32_16x16x32_bf16(Ah1, Bh, g1, 0, 0, 0);
    g1 = __builtin_amdgcn_mfma_f32_16x16x32_bf16(Ah1, Bl, g1, 0, 0, 0);
    g1 = __builtin_amdgcn_mfma_f32_16x16x32_bf16(Al1, Bh, g1, 0, 0, 0);
    const float cnv = cnorm[cb0 + col];
    #pragma unroll
    for (int r = 0; r < 4; ++r) {
      const float d0 = fmaf(-2.f, g0[r], cnv);
      if (d0 < bd0[r]) { bd0[r] = d0; bj0[r] = t; }
      const float d1 = fmaf(-2.f, g1[r], cnv);
      if (d1 < bd1[r]) { bd1[r] = d1; bj1[r] = t; }
    }
  }

  int jl0[4], jl1[4];
  #pragma unroll
  for (int r = 0; r < 4; ++r) { jl0[r] = bj0[r] * 16 + col; jl1[r] = bj1[r] * 16 + col; }
  #pragma unroll
  for (int mm = 1; mm <= 8; mm <<= 1) {
    #pragma unroll
    for (int r = 0; r < 4; ++r) {
      float od = __shfl_xor(bd0[r], mm, 64); int oj = __shfl_xor(jl0[r], mm, 64);
      if (od < bd0[r] || (od == bd0[r] && oj < jl0[r])) { bd0[r] = od; jl0[r] = oj; }
      od = __shfl_xor(bd1[r], mm, 64); oj = __shfl_xor(jl1[r], mm, 64);
      if (od < bd1[r] || (od == bd1[r] && oj < jl1[r])) { bd1[r] = od; jl1[r] = oj; }
    }
  }
  if (col == 0) {
    #pragma unroll
    for (int r = 0; r < 4; ++r) {
      const int pA = p0 + quad * 4 + r;
      pd[(long)pA * SCH + cid] = bd0[r];
      pi[(long)pA * SCH + cid] = jb + jl0[r];
      const int pB = pA + 16;
      pd[(long)pB * SCH + cid] = bd1[r];
      pi[(long)pB * SCH + cid] = jb + jl1[r];
    }
  }
}

// ---------------- exact-fp32 rescue + argmin finalize + zq gather + loss partials ------
__global__ __launch_bounds__(256) void k_rescue(
    const float* __restrict__ zc, const float* __restrict__ cb,
    const float* __restrict__ cnorm,
    const float* __restrict__ pd, const int* __restrict__ pi,
    float* __restrict__ zq, float* __restrict__ lpart) {
  const int lane = threadIdx.x & 63;
  const int wv   = threadIdx.x >> 6;
  const int p    = blockIdx.x * 4 + wv;

  const float m = pd[(long)p * SCH + lane];
  float dstar = m;
  #pragma unroll
  for (int mm = 1; mm <= 32; mm <<= 1) dstar = fminf(dstar, __shfl_xor(dstar, mm, 64));
  unsigned long long mask = __ballot(m <= dstar + MARGIN);

  float zr[CD];
  {
    const float4* z4 = (const float4*)(zc + (long)p * CD);
    #pragma unroll
    for (int q = 0; q < 8; ++q) {
      float4 v = z4[q];
      zr[4 * q + 0] = v.x; zr[4 * q + 1] = v.y; zr[4 * q + 2] = v.z; zr[4 * q + 3] = v.w;
    }
  }

  float bd = 1e30f;
  int   bj = 0x7fffffff;
  while (mask) {
    const int c = (int)__builtin_ctzll(mask);
    mask &= mask - 1;
    #pragma unroll
    for (int u = 0; u < 2; ++u) {
      const int j = c * CPC + u * 64 + lane;
      const float4* crow = (const float4*)(cb + (long)j * CD);
      float acc = 0.f;
      #pragma unroll
      for (int q = 0; q < 8; ++q) {
        float4 cv = crow[q];
        acc = fmaf(zr[4 * q + 0], cv.x, acc);
        acc = fmaf(zr[4 * q + 1], cv.y, acc);
        acc = fmaf(zr[4 * q + 2], cv.z, acc);
        acc = fmaf(zr[4 * q + 3], cv.w, acc);
      }
      const float d = fmaf(-2.f, acc, cnorm[j]);
      if (d < bd) { bd = d; bj = j; }
    }
  }
  #pragma unroll
  for (int mm = 1; mm <= 32; mm <<= 1) {
    const float od = __shfl_xor(bd, mm, 64);
    const int   oj = __shfl_xor(bj, mm, 64);
    if (od < bd || (od == bd && oj < bj)) { bd = od; bj = oj; }
  }

  float ls = 0.f;
  if (lane < 32) {
    const float cv = cb[(long)bj * CD + lane];
    const float zv = zc[(long)p * CD + lane];
    zq[(long)p * CD + lane] = cv;
    const float df = cv - zv;
    ls = df * df;
  }
  #pragma unroll
  for (int mm = 1; mm <= 32; mm <<= 1) ls += __shfl_xor(ls, mm, 64);
  if (lane == 0) lpart[p] = ls;
}

// ---------------- out = z_q @ W_expand + b_expand ; block 3072 = loss reduce ----------
__global__ __launch_bounds__(256) void k_expand(
    const float* __restrict__ zq,
    const float* __restrict__ We,
    const float* __restrict__ be,
    const float* __restrict__ lpart,
    float* __restrict__ out,
    float* __restrict__ out_loss) {
  __shared__ double redd[4];
  const int t = threadIdx.x;
  if (blockIdx.x == 3072) {
    double v = 0.0;
    for (int k = t; k < M; k += 256) v += (double)lpart[k];
    #pragma unroll
    for (int mm = 1; mm <= 32; mm <<= 1) v += __shfl_xor(v, mm, 64);
    if ((t & 63) == 0) redd[t >> 6] = v;
    __syncthreads();
    if (t == 0)
      out_loss[0] = (float)(3.0 * (redd[0] + redd[1] + redd[2] + redd[3]) / (double)(M * CD));
    return;
  }
  const int rb = blockIdx.x & 1023;        // 1024 row-blocks
  const int g  = blockIdx.x >> 10;         // 0..2 col-groups
  const int c  = g * 256 + t;
  const int r0 = rb * 16;
  float w[CD];
  #pragma unroll
  for (int k = 0; k < CD; ++k) w[k] = We[k * CIN + c];
  const float bb = be[c];
  #pragma unroll 2
  for (int r = r0; r < r0 + 16; r += 2) {
    const float4* qa = (const float4*)(zq + (long)r * CD);
    const float4* qb = (const float4*)(zq + (long)(r + 1) * CD);
    float a0 = bb, a1 = bb;
    #pragma unroll
    for (int k4 = 0; k4 < 8; ++k4) {
      const float4 va = qa[k4];
      const float4 vb = qb[k4];
      a0 = fmaf(va.x, w[4 * k4 + 0], a0);
      a1 = fmaf(vb.x, w[4 * k4 + 0], a1);
      a0 = fmaf(va.y, w[4 * k4 + 1], a0);
      a1 = fmaf(vb.y, w[4 * k4 + 1], a1);
      a0 = fmaf(va.z, w[4 * k4 + 2], a0);
      a1 = fmaf(vb.z, w[4 * k4 + 2], a1);
      a0 = fmaf(va.w, w[4 * k4 + 3], a0);
      a1 = fmaf(vb.w, w[4 * k4 + 3], a1);
    }
    out[(long)r * CIN + c]       = a0;
    out[(long)(r + 1) * CIN + c] = a1;
  }
}

extern "C" void kernel_launch(void* const* d_in, const int* in_sizes, int n_in,
                              void* d_out, int out_size, void* d_ws, size_t ws_size,
                              hipStream_t stream) {
  const float* z   = (const float*)d_in[0];
  const float* emb = (const float*)d_in[1];
  const float* Wc  = (const float*)d_in[2];
  const float* bc  = (const float*)d_in[3];
  const float* Wct = (const float*)d_in[4];
  const float* bct = (const float*)d_in[5];
  const float* We  = (const float*)d_in[6];
  const float* be  = (const float*)d_in[7];
  float* out = (float*)d_out;

  float* cb    = (float*)d_ws;              // NE*CD        = 262144 f
  float* cnorm = cb + NE * CD;              // NE           = 8192 f
  float* zc    = cnorm + NE;                // M*CD         = 524288 f
  float* zq    = zc + M * CD;               // M*CD         = 524288 f
  float* pd    = zq + M * CD;               // M*SCH        = 1048576 f
  float* lpart = pd + (long)M * SCH;        // M            = 16384 f
  int*   pi    = (int*)(lpart + M);         // M*SCH        = 1048576 i
  unsigned short* zh = (unsigned short*)(pi + (long)M * SCH);  // M*CD ushort
  unsigned short* zl = zh + M * CD;
  unsigned short* ch = zl + M * CD;         // NE*CD ushort
  unsigned short* cl = ch + NE * CD;

  k_pre<<<1536, 256, 0, stream>>>(emb, Wct, bct, z, Wc, bc,
                                  cb, cnorm, ch, cl, zc, zh, zl);
  k_argmin<<<(M / PTB) * SCH, 256, 0, stream>>>(zh, zl, ch, cl, cnorm, pd, pi);
  k_rescue<<<M / 4, 256, 0, stream>>>(zc, cb, cnorm, pd, pi, zq, lpart);
  k_expand<<<3072 + 1, 256, 0, stream>>>(zq, We, be, lpart, out, out + (long)M * CIN);
}

// Round 2
// 237.935 us; speedup vs baseline: 1.1797x; 1.0529x over previous
//
#include <hip/hip_runtime.h>

constexpr int CIN = 768;
constexpr int CD  = 32;
constexpr int NE  = 8192;
constexpr int M   = 16384;      // B*N = 64*256
constexpr int SCH = 64;         // code chunks for argmin
constexpr int CPC = NE / SCH;   // 128 codes per chunk
constexpr int PTB = 128;        // points per argmin block (4 waves x 32)
#define MARGIN 0.05f

typedef short short8 __attribute__((ext_vector_type(8)));
typedef float f32x4  __attribute__((ext_vector_type(4)));

// RNE split of fp32 into bf16 hi + bf16 lo-residual
__device__ inline void split_bf16(float x, unsigned short& h, unsigned short& l) {
  unsigned u = __float_as_uint(x);
  unsigned hb = (u + 0x7FFFu + ((u >> 16) & 1u)) >> 16;
  float hf = __uint_as_float(hb << 16);
  float r = x - hf;
  unsigned u2 = __float_as_uint(r);
  unsigned lb = (u2 + 0x7FFFu + ((u2 >> 16) & 1u)) >> 16;
  h = (unsigned short)hb;
  l = (unsigned short)lb;
}

// ---------------- fused: compress (blocks 0..511) + codebook (512..1535) ----
// compress: block = 32 rows, 256 threads = 16 row-pairs x 16 K-splits of 48.
//   W_compress staged per 12-K chunk into LDS (wave-uniform reads, broadcast).
//   z loads: 1 float4 per lane, 64 distinct rows/instr -> no broadcast waste.
//   K-split partials reduced via shfl_xor (4 splits/wave) + LDS (4 waves).
__global__ __launch_bounds__(256, 2) void k_pre(
    const float* __restrict__ emb, const float* __restrict__ Wct,
    const float* __restrict__ bct,
    const float* __restrict__ z, const float* __restrict__ Wc,
    const float* __restrict__ bc,
    float* __restrict__ cb, float* __restrict__ cnorm,
    unsigned short* __restrict__ ch, unsigned short* __restrict__ cl,
    float* __restrict__ zc, unsigned short* __restrict__ zh,
    unsigned short* __restrict__ zl) {
  // ws: [16 splits][12 k][36 pad] = 6912 f (27.6 KB); red reuse: [4][32][36] = 4608 f
  __shared__ float smem[6912];
  const int t = threadIdx.x;
  if (blockIdx.x >= 512) {
    // ---- codebook = emb @ W_ct + b_ct ----
    for (int i = t; i < CD * CD; i += 256) smem[i] = Wct[i];
    __syncthreads();
    const int g   = (blockIdx.x - 512) * 256 + t;
    const int row = g >> 5;
    const int col = g & 31;
    float acc = bct[col];
    const float* er = emb + row * CD;
    #pragma unroll
    for (int k = 0; k < CD; ++k) acc = fmaf(er[k], smem[k * CD + col], acc);
    cb[g] = acc;
    unsigned short h, l;
    split_bf16(acc, h, l);
    ch[g] = h; cl[g] = l;
    float v = acc * acc;
    #pragma unroll
    for (int m = 16; m >= 1; m >>= 1) v += __shfl_xor(v, m, 64);
    if (col == 0) cnorm[row] = v;
    return;
  }
  // ---- zc = z @ W_compress + b ----
  const int p   = t & 15;                  // row-pair 0..15
  const int spl = t >> 4;                  // K-split 0..15
  const int wid = t >> 6;                  // wave 0..3
  const int r0  = blockIdx.x * 32;
  const int row = r0 + 2 * p;
  const float* z0 = z + (long)row * CIN + spl * 48;
  const float* z1 = z0 + CIN;
  float acc0[32], acc1[32];
  if (spl == 0) {
    #pragma unroll
    for (int c = 0; c < 32; ++c) { acc0[c] = bc[c]; acc1[c] = bc[c]; }
  } else {
    #pragma unroll
    for (int c = 0; c < 32; ++c) { acc0[c] = 0.f; acc1[c] = 0.f; }
  }
  for (int cch = 0; cch < 4; ++cch) {      // 4 chunks of 12 k per split
    // z prefetch for this chunk (independent of LDS staging)
    float4 a0[3], a1[3];
    #pragma unroll
    for (int q = 0; q < 3; ++q) {
      a0[q] = *(const float4*)(z0 + cch * 12 + q * 4);
      a1[q] = *(const float4*)(z1 + cch * 12 + q * 4);
    }
    // stage W chunk: 16 splits x 12 k x 32 c = 1536 float4
    #pragma unroll
    for (int i = 0; i < 6; ++i) {
      const int f   = t + i * 256;
      const int sp2 = f / 96;
      const int rem = f - sp2 * 96;
      const int kk  = rem >> 3;
      const int c4  = rem & 7;
      const float4 wvv = *(const float4*)(Wc + ((sp2 * 48 + cch * 12 + kk) << 5) + (c4 << 2));
      *(float4*)(smem + sp2 * 432 + kk * 36 + (c4 << 2)) = wvv;
    }
    __syncthreads();
    const float* wsb = smem + spl * 432;
    #pragma unroll
    for (int q = 0; q < 3; ++q) {
      #pragma unroll
      for (int j = 0; j < 4; ++j) {
        const float zk0 = (j == 0) ? a0[q].x : (j == 1) ? a0[q].y : (j == 2) ? a0[q].z : a0[q].w;
        const float zk1 = (j == 0) ? a1[q].x : (j == 1) ? a1[q].y : (j == 2) ? a1[q].z : a1[q].w;
        const float* wr = wsb + (q * 4 + j) * 36;
        #pragma unroll
        for (int c4i = 0; c4i < 8; ++c4i) {
          const float4 wvv = *(const float4*)(wr + (c4i << 2));
          acc0[c4i * 4 + 0] = fmaf(zk0, wvv.x, acc0[c4i * 4 + 0]);
          acc0[c4i * 4 + 1] = fmaf(zk0, wvv.y, acc0[c4i * 4 + 1]);
          acc0[c4i * 4 + 2] = fmaf(zk0, wvv.z, acc0[c4i * 4 + 2]);
          acc0[c4i * 4 + 3] = fmaf(zk0, wvv.w, acc0[c4i * 4 + 3]);
          acc1[c4i * 4 + 0] = fmaf(zk1, wvv.x, acc1[c4i * 4 + 0]);
          acc1[c4i * 4 + 1] = fmaf(zk1, wvv.y, acc1[c4i * 4 + 1]);
          acc1[c4i * 4 + 2] = fmaf(zk1, wvv.z, acc1[c4i * 4 + 2]);
          acc1[c4i * 4 + 3] = fmaf(zk1, wvv.w, acc1[c4i * 4 + 3]);
        }
      }
    }
    __syncthreads();
  }
  // reduce 4 splits within each wave (lanes differ in bits 4,5 of t)
  #pragma unroll
  for (int mk = 16; mk <= 32; mk <<= 1) {
    #pragma unroll
    for (int c = 0; c < 32; ++c) {
      acc0[c] += __shfl_xor(acc0[c], mk, 64);
      acc1[c] += __shfl_xor(acc1[c], mk, 64);
    }
  }
  // wave partials -> LDS (sub-split 0 lanes hold the per-wave sums)
  if (((t >> 4) & 3) == 0) {
    float* rr0 = smem + wid * 1152 + (2 * p) * 36;
    float* rr1 = rr0 + 36;
    #pragma unroll
    for (int c4i = 0; c4i < 8; ++c4i) {
      float4 v0, v1;
      v0.x = acc0[c4i * 4 + 0]; v0.y = acc0[c4i * 4 + 1];
      v0.z = acc0[c4i * 4 + 2]; v0.w = acc0[c4i * 4 + 3];
      v1.x = acc1[c4i * 4 + 0]; v1.y = acc1[c4i * 4 + 1];
      v1.z = acc1[c4i * 4 + 2]; v1.w = acc1[c4i * 4 + 3];
      *(float4*)(rr0 + (c4i << 2)) = v0;
      *(float4*)(rr1 + (c4i << 2)) = v1;
    }
  }
  __syncthreads();
  // gather: 256 threads = 32 rows x 8 col-quads, sum 4 wave-partials, store
  const int grow = t >> 3;
  const int gc4  = t & 7;
  const float* rb = smem + grow * 36 + (gc4 << 2);
  const float4 s0 = *(const float4*)(rb);
  const float4 s1 = *(const float4*)(rb + 1152);
  const float4 s2 = *(const float4*)(rb + 2304);
  const float4 s3 = *(const float4*)(rb + 3456);
  float4 sv;
  sv.x = ((s0.x + s1.x) + s2.x) + s3.x;
  sv.y = ((s0.y + s1.y) + s2.y) + s3.y;
  sv.z = ((s0.z + s1.z) + s2.z) + s3.z;
  sv.w = ((s0.w + s1.w) + s2.w) + s3.w;
  const long idx = (long)(r0 + grow) * CD + (gc4 << 2);
  *(float4*)(zc + idx) = sv;
  ushort4 h4, l4;
  split_bf16(sv.x, h4.x, l4.x);
  split_bf16(sv.y, h4.y, l4.y);
  split_bf16(sv.z, h4.z, l4.z);
  split_bf16(sv.w, h4.w, l4.w);
  *(ushort4*)(zh + idx) = h4;
  *(ushort4*)(zl + idx) = l4;
}

// ---------------- MFMA approx distances + per-chunk min (no index tracking) ----------
// grid = (M/PTB=128) x SCH=64 -> 8192 blocks; wave handles 32 points x 128 codes.
// pd only: k_rescue re-derives exact indices for candidate chunks, so per-tile
// index bookkeeping is dead work (2 VALU/distance instead of ~4-5).
__global__ __launch_bounds__(256) void k_argmin(
    const unsigned short* __restrict__ zh, const unsigned short* __restrict__ zl,
    const unsigned short* __restrict__ ch, const unsigned short* __restrict__ cl,
    const float* __restrict__ cnorm,
    float* __restrict__ pd) {
  const int pb   = blockIdx.x & (M / PTB - 1);   // 0..127
  const int cid  = blockIdx.x >> 7;              // 0..63
  const int lane = threadIdx.x & 63;
  const int wv   = threadIdx.x >> 6;
  const int col  = lane & 15;
  const int quad = lane >> 4;
  const int p0   = pb * PTB + wv * 32;

  const short8 Ah0 = *(const short8*)(zh + (long)(p0 + col) * CD + quad * 8);
  const short8 Al0 = *(const short8*)(zl + (long)(p0 + col) * CD + quad * 8);
  const short8 Ah1 = *(const short8*)(zh + (long)(p0 + 16 + col) * CD + quad * 8);
  const short8 Al1 = *(const short8*)(zl + (long)(p0 + 16 + col) * CD + quad * 8);

  const int jb = cid * CPC;
  float bd0[4], bd1[4];
  #pragma unroll
  for (int r = 0; r < 4; ++r) { bd0[r] = 1e30f; bd1[r] = 1e30f; }

  #pragma unroll
  for (int t = 0; t < CPC / 16; ++t) {           // 8 tiles of 16 codes
    const int cb0 = jb + t * 16;
    const short8 Bh = *(const short8*)(ch + (long)(cb0 + col) * CD + quad * 8);
    const short8 Bl = *(const short8*)(cl + (long)(cb0 + col) * CD + quad * 8);
    f32x4 g0 = {0.f, 0.f, 0.f, 0.f};
    f32x4 g1 = {0.f, 0.f, 0.f, 0.f};
    g0 = __builtin_amdgcn_mfma_f32_16x16x32_bf16(Ah0, Bh, g0, 0, 0, 0);
    g0 = __builtin_amdgcn_mfma_f32_16x16x32_bf16(Ah0, Bl, g0, 0, 0, 0);
    g0 = __builtin_amdgcn_mfma_f32_16x16x32_bf16(Al0, Bh, g0, 0, 0, 0);
    g1 = __builtin_amdgcn_mfma_f32_16x16x32_bf16(Ah1, Bh, g1, 0, 0, 0);
    g1 = __builtin_amdgcn_mfma_f32_16x16x32_bf16(Ah1, Bl, g1, 0, 0, 0);
    g1 = __builtin_amdgcn_mfma_f32_16x16x32_bf16(Al1, Bh, g1, 0, 0, 0);
    const float cnv = cnorm[cb0 + col];
    #pragma unroll
    for (int r = 0; r < 4; ++r) {
      bd0[r] = fminf(bd0[r], fmaf(-2.f, g0[r], cnv));
      bd1[r] = fminf(bd1[r], fmaf(-2.f, g1[r], cnv));
    }
  }

  // min across the 16 code-columns (lane bits 0..3)
  #pragma unroll
  for (int mm = 1; mm <= 8; mm <<= 1) {
    #pragma unroll
    for (int r = 0; r < 4; ++r) {
      bd0[r] = fminf(bd0[r], __shfl_xor(bd0[r], mm, 64));
      bd1[r] = fminf(bd1[r], __shfl_xor(bd1[r], mm, 64));
    }
  }
  if (col == 0) {
    #pragma unroll
    for (int r = 0; r < 4; ++r) {
      const int pA = p0 + quad * 4 + r;
      pd[(long)pA * SCH + cid] = bd0[r];
      const int pB = pA + 16;
      pd[(long)pB * SCH + cid] = bd1[r];
    }
  }
}

// ---------------- exact-fp32 rescue + argmin finalize + zq gather + loss partials ------
__global__ __launch_bounds__(256) void k_rescue(
    const float* __restrict__ zc, const float* __restrict__ cb,
    const float* __restrict__ cnorm,
    const float* __restrict__ pd,
    float* __restrict__ zq, float* __restrict__ lpart) {
  const int lane = threadIdx.x & 63;
  const int wv   = threadIdx.x >> 6;
  const int p    = blockIdx.x * 4 + wv;

  const float m = pd[(long)p * SCH + lane];
  float dstar = m;
  #pragma unroll
  for (int mm = 1; mm <= 32; mm <<= 1) dstar = fminf(dstar, __shfl_xor(dstar, mm, 64));
  unsigned long long mask = __ballot(m <= dstar + MARGIN);

  float zr[CD];
  {
    const float4* z4 = (const float4*)(zc + (long)p * CD);
    #pragma unroll
    for (int q = 0; q < 8; ++q) {
      float4 v = z4[q];
      zr[4 * q + 0] = v.x; zr[4 * q + 1] = v.y; zr[4 * q + 2] = v.z; zr[4 * q + 3] = v.w;
    }
  }

  float bd = 1e30f;
  int   bj = 0x7fffffff;
  while (mask) {
    const int c = (int)__builtin_ctzll(mask);
    mask &= mask - 1;
    #pragma unroll
    for (int u = 0; u < 2; ++u) {
      const int j = c * CPC + u * 64 + lane;
      const float4* crow = (const float4*)(cb + (long)j * CD);
      float acc = 0.f;
      #pragma unroll
      for (int q = 0; q < 8; ++q) {
        float4 cv = crow[q];
        acc = fmaf(zr[4 * q + 0], cv.x, acc);
        acc = fmaf(zr[4 * q + 1], cv.y, acc);
        acc = fmaf(zr[4 * q + 2], cv.z, acc);
        acc = fmaf(zr[4 * q + 3], cv.w, acc);
      }
      const float d = fmaf(-2.f, acc, cnorm[j]);
      if (d < bd) { bd = d; bj = j; }
    }
  }
  #pragma unroll
  for (int mm = 1; mm <= 32; mm <<= 1) {
    const float od = __shfl_xor(bd, mm, 64);
    const int   oj = __shfl_xor(bj, mm, 64);
    if (od < bd || (od == bd && oj < bj)) { bd = od; bj = oj; }
  }

  float ls = 0.f;
  if (lane < 32) {
    const float cv = cb[(long)bj * CD + lane];
    const float zv = zc[(long)p * CD + lane];
    zq[(long)p * CD + lane] = cv;
    const float df = cv - zv;
    ls = df * df;
  }
  #pragma unroll
  for (int mm = 1; mm <= 32; mm <<= 1) ls += __shfl_xor(ls, mm, 64);
  if (lane == 0) lpart[p] = ls;
}

// ---------------- out = z_q @ W_expand + b_expand ; block 3072 = loss reduce ----------
__global__ __launch_bounds__(256) void k_expand(
    const float* __restrict__ zq,
    const float* __restrict__ We,
    const float* __restrict__ be,
    const float* __restrict__ lpart,
    float* __restrict__ out,
    float* __restrict__ out_loss) {
  __shared__ double redd[4];
  const int t = threadIdx.x;
  if (blockIdx.x == 3072) {
    double v = 0.0;
    for (int k = t; k < M; k += 256) v += (double)lpart[k];
    #pragma unroll
    for (int mm = 1; mm <= 32; mm <<= 1) v += __shfl_xor(v, mm, 64);
    if ((t & 63) == 0) redd[t >> 6] = v;
    __syncthreads();
    if (t == 0)
      out_loss[0] = (float)(3.0 * (redd[0] + redd[1] + redd[2] + redd[3]) / (double)(M * CD));
    return;
  }
  const int rb = blockIdx.x & 1023;        // 1024 row-blocks
  const int g  = blockIdx.x >> 10;         // 0..2 col-groups
  const int c  = g * 256 + t;
  const int r0 = rb * 16;
  float w[CD];
  #pragma unroll
  for (int k = 0; k < CD; ++k) w[k] = We[k * CIN + c];
  const float bb = be[c];
  #pragma unroll 2
  for (int r = r0; r < r0 + 16; r += 2) {
    const float4* qa = (const float4*)(zq + (long)r * CD);
    const float4* qb = (const float4*)(zq + (long)(r + 1) * CD);
    float a0 = bb, a1 = bb;
    #pragma unroll
    for (int k4 = 0; k4 < 8; ++k4) {
      const float4 va = qa[k4];
      const float4 vb = qb[k4];
      a0 = fmaf(va.x, w[4 * k4 + 0], a0);
      a1 = fmaf(vb.x, w[4 * k4 + 0], a1);
      a0 = fmaf(va.y, w[4 * k4 + 1], a0);
      a1 = fmaf(vb.y, w[4 * k4 + 1], a1);
      a0 = fmaf(va.z, w[4 * k4 + 2], a0);
      a1 = fmaf(vb.z, w[4 * k4 + 2], a1);
      a0 = fmaf(va.w, w[4 * k4 + 3], a0);
      a1 = fmaf(vb.w, w[4 * k4 + 3], a1);
    }
    out[(long)r * CIN + c]       = a0;
    out[(long)(r + 1) * CIN + c] = a1;
  }
}

extern "C" void kernel_launch(void* const* d_in, const int* in_sizes, int n_in,
                              void* d_out, int out_size, void* d_ws, size_t ws_size,
                              hipStream_t stream) {
  const float* z   = (const float*)d_in[0];
  const float* emb = (const float*)d_in[1];
  const float* Wc  = (const float*)d_in[2];
  const float* bc  = (const float*)d_in[3];
  const float* Wct = (const float*)d_in[4];
  const float* bct = (const float*)d_in[5];
  const float* We  = (const float*)d_in[6];
  const float* be  = (const float*)d_in[7];
  float* out = (float*)d_out;

  float* cb    = (float*)d_ws;              // NE*CD        = 262144 f
  float* cnorm = cb + NE * CD;              // NE           = 8192 f
  float* zc    = cnorm + NE;                // M*CD         = 524288 f
  float* zq    = zc + M * CD;               // M*CD         = 524288 f
  float* pd    = zq + M * CD;               // M*SCH        = 1048576 f
  float* lpart = pd + (long)M * SCH;        // M            = 16384 f
  // (former pi slot kept as padding so downstream offsets are unchanged)
  unsigned short* zh = (unsigned short*)(lpart + M + (long)M * SCH);  // M*CD ushort
  unsigned short* zl = zh + M * CD;
  unsigned short* ch = zl + M * CD;         // NE*CD ushort
  unsigned short* cl = ch + NE * CD;

  k_pre<<<1536, 256, 0, stream>>>(emb, Wct, bct, z, Wc, bc,
                                  cb, cnorm, ch, cl, zc, zh, zl);
  k_argmin<<<(M / PTB) * SCH, 256, 0, stream>>>(zh, zl, ch, cl, cnorm, pd);
  k_rescue<<<M / 4, 256, 0, stream>>>(zc, cb, cnorm, pd, zq, lpart);
  k_expand<<<3072 + 1, 256, 0, stream>>>(zq, We, be, lpart, out, out + (long)M * CIN);
}

// Round 3
// 221.130 us; speedup vs baseline: 1.2694x; 1.0760x over previous
//
#include <hip/hip_runtime.h>

constexpr int CIN = 768;
constexpr int CD  = 32;
constexpr int NE  = 8192;
constexpr int M   = 16384;      // B*N = 64*256
constexpr int SCH = 64;         // code chunks for argmin
constexpr int CPC = NE / SCH;   // 128 codes per chunk
constexpr int PTB = 128;        // points per argmin block (4 waves x 32)
#define MARGIN 0.05f

typedef short short8 __attribute__((ext_vector_type(8)));
typedef float f32x4  __attribute__((ext_vector_type(4)));

// RNE split of fp32 into bf16 hi + bf16 lo-residual
__device__ inline void split_bf16(float x, unsigned short& h, unsigned short& l) {
  unsigned u = __float_as_uint(x);
  unsigned hb = (u + 0x7FFFu + ((u >> 16) & 1u)) >> 16;
  float hf = __uint_as_float(hb << 16);
  float r = x - hf;
  unsigned u2 = __float_as_uint(r);
  unsigned lb = (u2 + 0x7FFFu + ((u2 >> 16) & 1u)) >> 16;
  h = (unsigned short)hb;
  l = (unsigned short)lb;
}

__device__ inline void gload_lds16(const void* g, void* l) {
  __builtin_amdgcn_global_load_lds(
      (const __attribute__((address_space(1))) unsigned int*)g,
      (__attribute__((address_space(3))) unsigned int*)l, 16, 0, 0);
}

// ---------------- fused: compress (0..511) + codebook (512..1535) + WeT split (1536..1538)
__global__ __launch_bounds__(256, 2) void k_pre(
    const float* __restrict__ emb, const float* __restrict__ Wct,
    const float* __restrict__ bct,
    const float* __restrict__ z, const float* __restrict__ Wc,
    const float* __restrict__ bc, const float* __restrict__ We,
    float* __restrict__ cb, float* __restrict__ cnorm,
    unsigned short* __restrict__ ch, unsigned short* __restrict__ cl,
    float* __restrict__ zc, unsigned short* __restrict__ zh,
    unsigned short* __restrict__ zl,
    unsigned short* __restrict__ WeTh, unsigned short* __restrict__ WeTl) {
  __shared__ float smem[6912];
  const int t = threadIdx.x;
  if (blockIdx.x >= 1536) {
    // ---- transpose-split W_expand: WeT[n][k] = split(We[k][n]) ----
    const int n = (blockIdx.x - 1536) * 256 + t;
    #pragma unroll
    for (int k = 0; k < CD; ++k) {
      unsigned short h, l;
      split_bf16(We[(long)k * CIN + n], h, l);
      WeTh[n * CD + k] = h;
      WeTl[n * CD + k] = l;
    }
    return;
  }
  if (blockIdx.x >= 512) {
    // ---- codebook = emb @ W_ct + b_ct ----
    for (int i = t; i < CD * CD; i += 256) smem[i] = Wct[i];
    __syncthreads();
    const int g   = (blockIdx.x - 512) * 256 + t;
    const int row = g >> 5;
    const int col = g & 31;
    float acc = bct[col];
    const float* er = emb + row * CD;
    #pragma unroll
    for (int k = 0; k < CD; ++k) acc = fmaf(er[k], smem[k * CD + col], acc);
    cb[g] = acc;
    unsigned short h, l;
    split_bf16(acc, h, l);
    ch[g] = h; cl[g] = l;
    float v = acc * acc;
    #pragma unroll
    for (int m = 16; m >= 1; m >>= 1) v += __shfl_xor(v, m, 64);
    if (col == 0) cnorm[row] = v;
    return;
  }
  // ---- zc = z @ W_compress + b ----
  const int p   = t & 15;                  // row-pair 0..15
  const int spl = t >> 4;                  // K-split 0..15
  const int wid = t >> 6;                  // wave 0..3
  const int r0  = blockIdx.x * 32;
  const int row = r0 + 2 * p;
  const float* z0 = z + (long)row * CIN + spl * 48;
  const float* z1 = z0 + CIN;
  float acc0[32], acc1[32];
  if (spl == 0) {
    #pragma unroll
    for (int c = 0; c < 32; ++c) { acc0[c] = bc[c]; acc1[c] = bc[c]; }
  } else {
    #pragma unroll
    for (int c = 0; c < 32; ++c) { acc0[c] = 0.f; acc1[c] = 0.f; }
  }
  for (int cch = 0; cch < 4; ++cch) {      // 4 chunks of 12 k per split
    float4 a0[3], a1[3];
    #pragma unroll
    for (int q = 0; q < 3; ++q) {
      a0[q] = *(const float4*)(z0 + cch * 12 + q * 4);
      a1[q] = *(const float4*)(z1 + cch * 12 + q * 4);
    }
    #pragma unroll
    for (int i = 0; i < 6; ++i) {
      const int f   = t + i * 256;
      const int sp2 = f / 96;
      const int rem = f - sp2 * 96;
      const int kk  = rem >> 3;
      const int c4  = rem & 7;
      const float4 wvv = *(const float4*)(Wc + ((sp2 * 48 + cch * 12 + kk) << 5) + (c4 << 2));
      *(float4*)(smem + sp2 * 432 + kk * 36 + (c4 << 2)) = wvv;
    }
    __syncthreads();
    const float* wsb = smem + spl * 432;
    #pragma unroll
    for (int q = 0; q < 3; ++q) {
      #pragma unroll
      for (int j = 0; j < 4; ++j) {
        const float zk0 = (j == 0) ? a0[q].x : (j == 1) ? a0[q].y : (j == 2) ? a0[q].z : a0[q].w;
        const float zk1 = (j == 0) ? a1[q].x : (j == 1) ? a1[q].y : (j == 2) ? a1[q].z : a1[q].w;
        const float* wr = wsb + (q * 4 + j) * 36;
        #pragma unroll
        for (int c4i = 0; c4i < 8; ++c4i) {
          const float4 wvv = *(const float4*)(wr + (c4i << 2));
          acc0[c4i * 4 + 0] = fmaf(zk0, wvv.x, acc0[c4i * 4 + 0]);
          acc0[c4i * 4 + 1] = fmaf(zk0, wvv.y, acc0[c4i * 4 + 1]);
          acc0[c4i * 4 + 2] = fmaf(zk0, wvv.z, acc0[c4i * 4 + 2]);
          acc0[c4i * 4 + 3] = fmaf(zk0, wvv.w, acc0[c4i * 4 + 3]);
          acc1[c4i * 4 + 0] = fmaf(zk1, wvv.x, acc1[c4i * 4 + 0]);
          acc1[c4i * 4 + 1] = fmaf(zk1, wvv.y, acc1[c4i * 4 + 1]);
          acc1[c4i * 4 + 2] = fmaf(zk1, wvv.z, acc1[c4i * 4 + 2]);
          acc1[c4i * 4 + 3] = fmaf(zk1, wvv.w, acc1[c4i * 4 + 3]);
        }
      }
    }
    __syncthreads();
  }
  #pragma unroll
  for (int mk = 16; mk <= 32; mk <<= 1) {
    #pragma unroll
    for (int c = 0; c < 32; ++c) {
      acc0[c] += __shfl_xor(acc0[c], mk, 64);
      acc1[c] += __shfl_xor(acc1[c], mk, 64);
    }
  }
  if (((t >> 4) & 3) == 0) {
    float* rr0 = smem + wid * 1152 + (2 * p) * 36;
    float* rr1 = rr0 + 36;
    #pragma unroll
    for (int c4i = 0; c4i < 8; ++c4i) {
      float4 v0, v1;
      v0.x = acc0[c4i * 4 + 0]; v0.y = acc0[c4i * 4 + 1];
      v0.z = acc0[c4i * 4 + 2]; v0.w = acc0[c4i * 4 + 3];
      v1.x = acc1[c4i * 4 + 0]; v1.y = acc1[c4i * 4 + 1];
      v1.z = acc1[c4i * 4 + 2]; v1.w = acc1[c4i * 4 + 3];
      *(float4*)(rr0 + (c4i << 2)) = v0;
      *(float4*)(rr1 + (c4i << 2)) = v1;
    }
  }
  __syncthreads();
  const int grow = t >> 3;
  const int gc4  = t & 7;
  const float* rb = smem + grow * 36 + (gc4 << 2);
  const float4 s0 = *(const float4*)(rb);
  const float4 s1 = *(const float4*)(rb + 1152);
  const float4 s2 = *(const float4*)(rb + 2304);
  const float4 s3 = *(const float4*)(rb + 3456);
  float4 sv;
  sv.x = ((s0.x + s1.x) + s2.x) + s3.x;
  sv.y = ((s0.y + s1.y) + s2.y) + s3.y;
  sv.z = ((s0.z + s1.z) + s2.z) + s3.z;
  sv.w = ((s0.w + s1.w) + s2.w) + s3.w;
  const long idx = (long)(r0 + grow) * CD + (gc4 << 2);
  *(float4*)(zc + idx) = sv;
  // zh/zl hold split(-2*zc): folds the -2 scale into the MFMA A-operand
  ushort4 h4, l4;
  split_bf16(-2.f * sv.x, h4.x, l4.x);
  split_bf16(-2.f * sv.y, h4.y, l4.y);
  split_bf16(-2.f * sv.z, h4.z, l4.z);
  split_bf16(-2.f * sv.w, h4.w, l4.w);
  *(ushort4*)(zh + idx) = h4;
  *(ushort4*)(zl + idx) = l4;
}

// ---------------- MFMA approx distances + per-chunk min ----------------
// B chunk (ch+cl, 16 KB) staged once per block into LDS via global_load_lds;
// cnorm folded into MFMA C-init; zh/zl pre-scaled by -2 -> inner loop is
// ds_read + MFMA + fmin only.
__global__ __launch_bounds__(256) void k_argmin(
    const unsigned short* __restrict__ zh, const unsigned short* __restrict__ zl,
    const unsigned short* __restrict__ ch, const unsigned short* __restrict__ cl,
    const float* __restrict__ cnorm,
    float* __restrict__ pd) {
  __shared__ __align__(16) unsigned short chs[CPC * CD];   // 8 KB
  __shared__ __align__(16) unsigned short cls[CPC * CD];   // 8 KB
  const int pb   = blockIdx.x & (M / PTB - 1);   // 0..127
  const int cid  = blockIdx.x >> 7;              // 0..63
  const int lane = threadIdx.x & 63;
  const int wv   = threadIdx.x >> 6;
  const int col  = lane & 15;
  const int quad = lane >> 4;
  const int p0   = pb * PTB + wv * 32;

  // stage code chunk: 2 sweeps x (ch, cl), linear copy, wave-uniform LDS base
  const char* chg = (const char*)ch + (long)cid * (CPC * CD * 2);
  const char* clg = (const char*)cl + (long)cid * (CPC * CD * 2);
  #pragma unroll
  for (int s = 0; s < 2; ++s) {
    const int lo = s * 4096 + wv * 1024;
    gload_lds16(chg + lo + lane * 16, (char*)chs + lo);
    gload_lds16(clg + lo + lane * 16, (char*)cls + lo);
  }

  const short8 Ah0 = *(const short8*)(zh + (long)(p0 + col) * CD + quad * 8);
  const short8 Al0 = *(const short8*)(zl + (long)(p0 + col) * CD + quad * 8);
  const short8 Ah1 = *(const short8*)(zh + (long)(p0 + 16 + col) * CD + quad * 8);
  const short8 Al1 = *(const short8*)(zl + (long)(p0 + 16 + col) * CD + quad * 8);

  const int jb = cid * CPC;
  float cnv[8];
  #pragma unroll
  for (int tt = 0; tt < 8; ++tt) cnv[tt] = cnorm[jb + tt * 16 + col];

  float bd0[4], bd1[4];
  #pragma unroll
  for (int r = 0; r < 4; ++r) { bd0[r] = 1e30f; bd1[r] = 1e30f; }

  __syncthreads();   // drains global_load_lds (vmcnt) + A/cnv loads

  #pragma unroll
  for (int tt = 0; tt < 8; ++tt) {           // 8 tiles of 16 codes from LDS
    const short8 Bh = *(const short8*)(chs + (tt * 16 + col) * CD + quad * 8);
    const short8 Bl = *(const short8*)(cls + (tt * 16 + col) * CD + quad * 8);
    const f32x4 c4 = {cnv[tt], cnv[tt], cnv[tt], cnv[tt]};
    f32x4 g0 = __builtin_amdgcn_mfma_f32_16x16x32_bf16(Ah0, Bh, c4, 0, 0, 0);
    g0 = __builtin_amdgcn_mfma_f32_16x16x32_bf16(Ah0, Bl, g0, 0, 0, 0);
    g0 = __builtin_amdgcn_mfma_f32_16x16x32_bf16(Al0, Bh, g0, 0, 0, 0);
    f32x4 g1 = __builtin_amdgcn_mfma_f32_16x16x32_bf16(Ah1, Bh, c4, 0, 0, 0);
    g1 = __builtin_amdgcn_mfma_f32_16x16x32_bf16(Ah1, Bl, g1, 0, 0, 0);
    g1 = __builtin_amdgcn_mfma_f32_16x16x32_bf16(Al1, Bh, g1, 0, 0, 0);
    #pragma unroll
    for (int r = 0; r < 4; ++r) {
      bd0[r] = fminf(bd0[r], g0[r]);
      bd1[r] = fminf(bd1[r], g1[r]);
    }
  }

  #pragma unroll
  for (int mm = 1; mm <= 8; mm <<= 1) {
    #pragma unroll
    for (int r = 0; r < 4; ++r) {
      bd0[r] = fminf(bd0[r], __shfl_xor(bd0[r], mm, 64));
      bd1[r] = fminf(bd1[r], __shfl_xor(bd1[r], mm, 64));
    }
  }
  if (col == 0) {
    #pragma unroll
    for (int r = 0; r < 4; ++r) {
      const int pA = p0 + quad * 4 + r;
      pd[(long)pA * SCH + cid] = bd0[r];
      const int pB = pA + 16;
      pd[(long)pB * SCH + cid] = bd1[r];
    }
  }
}

// ---------------- exact-fp32 rescue + argmin finalize + zq gather + loss partials ------
__global__ __launch_bounds__(256) void k_rescue(
    const float* __restrict__ zc, const float* __restrict__ cb,
    const float* __restrict__ cnorm,
    const float* __restrict__ pd,
    float* __restrict__ zq, unsigned short* __restrict__ zqh,
    unsigned short* __restrict__ zql, float* __restrict__ lpart) {
  const int lane = threadIdx.x & 63;
  const int wv   = threadIdx.x >> 6;
  const int p    = blockIdx.x * 4 + wv;

  const float m = pd[(long)p * SCH + lane];
  float dstar = m;
  #pragma unroll
  for (int mm = 1; mm <= 32; mm <<= 1) dstar = fminf(dstar, __shfl_xor(dstar, mm, 64));
  unsigned long long mask = __ballot(m <= dstar + MARGIN);

  float zr[CD];
  {
    const float4* z4 = (const float4*)(zc + (long)p * CD);
    #pragma unroll
    for (int q = 0; q < 8; ++q) {
      float4 v = z4[q];
      zr[4 * q + 0] = v.x; zr[4 * q + 1] = v.y; zr[4 * q + 2] = v.z; zr[4 * q + 3] = v.w;
    }
  }

  float bd = 1e30f;
  int   bj = 0x7fffffff;
  while (mask) {
    const int c = (int)__builtin_ctzll(mask);
    mask &= mask - 1;
    #pragma unroll
    for (int u = 0; u < 2; ++u) {
      const int j = c * CPC + u * 64 + lane;
      const float4* crow = (const float4*)(cb + (long)j * CD);
      float acc = 0.f;
      #pragma unroll
      for (int q = 0; q < 8; ++q) {
        float4 cv = crow[q];
        acc = fmaf(zr[4 * q + 0], cv.x, acc);
        acc = fmaf(zr[4 * q + 1], cv.y, acc);
        acc = fmaf(zr[4 * q + 2], cv.z, acc);
        acc = fmaf(zr[4 * q + 3], cv.w, acc);
      }
      const float d = fmaf(-2.f, acc, cnorm[j]);
      if (d < bd) { bd = d; bj = j; }
    }
  }
  #pragma unroll
  for (int mm = 1; mm <= 32; mm <<= 1) {
    const float od = __shfl_xor(bd, mm, 64);
    const int   oj = __shfl_xor(bj, mm, 64);
    if (od < bd || (od == bd && oj < bj)) { bd = od; bj = oj; }
  }

  float ls = 0.f;
  if (lane < 32) {
    const float cv = cb[(long)bj * CD + lane];
    const float zv = zc[(long)p * CD + lane];
    zq[(long)p * CD + lane] = cv;
    unsigned short hh, ll;
    split_bf16(cv, hh, ll);
    zqh[(long)p * CD + lane] = hh;
    zql[(long)p * CD + lane] = ll;
    const float df = cv - zv;
    ls = df * df;
  }
  #pragma unroll
  for (int mm = 1; mm <= 32; mm <<= 1) ls += __shfl_xor(ls, mm, 64);
  if (lane == 0) lpart[p] = ls;
}

// ---------------- out = z_q @ W_expand + b_expand via split-bf16 MFMA ----------------
// grid: 1024 row-blocks (16 rows each) + block 1024 = loss reduce.
// Per wave: 16 rows x 12 n-tiles of 16 cols; K=32 = one MFMA triple per tile,
// bias folded into MFMA C-init.
__global__ __launch_bounds__(256) void k_expand(
    const unsigned short* __restrict__ zqh, const unsigned short* __restrict__ zql,
    const unsigned short* __restrict__ WeTh, const unsigned short* __restrict__ WeTl,
    const float* __restrict__ be,
    const float* __restrict__ lpart,
    float* __restrict__ out,
    float* __restrict__ out_loss) {
  __shared__ double redd[4];
  const int t = threadIdx.x;
  if (blockIdx.x == 1024) {
    double v = 0.0;
    for (int k = t; k < M; k += 256) v += (double)lpart[k];
    #pragma unroll
    for (int mm = 1; mm <= 32; mm <<= 1) v += __shfl_xor(v, mm, 64);
    if ((t & 63) == 0) redd[t >> 6] = v;
    __syncthreads();
    if (t == 0)
      out_loss[0] = (float)(3.0 * (redd[0] + redd[1] + redd[2] + redd[3]) / (double)(M * CD));
    return;
  }
  const int lane = t & 63;
  const int wv   = t >> 6;
  const int col  = lane & 15;
  const int quad = lane >> 4;
  const int r0   = blockIdx.x * 16;

  const short8 Ah = *(const short8*)(zqh + (long)(r0 + col) * CD + quad * 8);
  const short8 Al = *(const short8*)(zql + (long)(r0 + col) * CD + quad * 8);

  #pragma unroll
  for (int tt = 0; tt < 12; ++tt) {
    const int n0 = (wv * 12 + tt) * 16;
    const short8 Bh = *(const short8*)(WeTh + (long)(n0 + col) * CD + quad * 8);
    const short8 Bl = *(const short8*)(WeTl + (long)(n0 + col) * CD + quad * 8);
    const float bv = be[n0 + col];
    const f32x4 c4 = {bv, bv, bv, bv};
    f32x4 g = __builtin_amdgcn_mfma_f32_16x16x32_bf16(Ah, Bh, c4, 0, 0, 0);
    g = __builtin_amdgcn_mfma_f32_16x16x32_bf16(Ah, Bl, g, 0, 0, 0);
    g = __builtin_amdgcn_mfma_f32_16x16x32_bf16(Al, Bh, g, 0, 0, 0);
    #pragma unroll
    for (int r = 0; r < 4; ++r)
      out[(long)(r0 + quad * 4 + r) * CIN + n0 + col] = g[r];
  }
}

extern "C" void kernel_launch(void* const* d_in, const int* in_sizes, int n_in,
                              void* d_out, int out_size, void* d_ws, size_t ws_size,
                              hipStream_t stream) {
  const float* z   = (const float*)d_in[0];
  const float* emb = (const float*)d_in[1];
  const float* Wc  = (const float*)d_in[2];
  const float* bc  = (const float*)d_in[3];
  const float* Wct = (const float*)d_in[4];
  const float* bct = (const float*)d_in[5];
  const float* We  = (const float*)d_in[6];
  const float* be  = (const float*)d_in[7];
  float* out = (float*)d_out;

  float* cb    = (float*)d_ws;              // NE*CD        = 262144 f
  float* cnorm = cb + NE * CD;              // NE           = 8192 f
  float* zc    = cnorm + NE;                // M*CD         = 524288 f
  float* zq    = zc + M * CD;               // M*CD         = 524288 f
  float* pd    = zq + M * CD;               // M*SCH        = 1048576 f
  float* lpart = pd + (long)M * SCH;        // M            = 16384 f
  unsigned short* zh   = (unsigned short*)(lpart + M);   // M*CD ush
  unsigned short* zl   = zh + M * CD;
  unsigned short* ch   = zl + M * CD;       // NE*CD ush
  unsigned short* cl   = ch + NE * CD;
  unsigned short* zqh  = cl + NE * CD;      // M*CD ush
  unsigned short* zql  = zqh + M * CD;
  unsigned short* WeTh = zql + M * CD;      // CIN*CD ush
  unsigned short* WeTl = WeTh + CIN * CD;

  k_pre<<<1539, 256, 0, stream>>>(emb, Wct, bct, z, Wc, bc, We,
                                  cb, cnorm, ch, cl, zc, zh, zl, WeTh, WeTl);
  k_argmin<<<(M / PTB) * SCH, 256, 0, stream>>>(zh, zl, ch, cl, cnorm, pd);
  k_rescue<<<M / 4, 256, 0, stream>>>(zc, cb, cnorm, pd, zq, zqh, zql, lpart);
  k_expand<<<1024 + 1, 256, 0, stream>>>(zqh, zql, WeTh, WeTl, be, lpart,
                                         out, out + (long)M * CIN);
}